// Round 7
// baseline (538.151 us; speedup 1.0000x reference)
//
#include <hip/hip_runtime.h>
#include <hip/hip_bf16.h>
#include <hip/hip_fp16.h>

// GCN autoencoder, R12:
//   memset(cnt,binCnt) -> fused1{gemm1 || bin->binBuf} -> fill_k(XCD-affine) ->
//   dinv_k -> aggG1(agg1 + fused gemm2 tail) -> agg2g(agg2 + fused decode)
//
// R11 post-mortem: filter-fill regressed fused1 to 145us (8x redundant edge
// scan + 7/8-divergent atomics); decode fusion was fine (agg2g below top-5).
// R12: (a) restore R8's measured-best fill path EXACTLY (bin-once via LDS
// histogram -> binBuf, then separate XCD-affine fill_k; both <83us there);
// (b) keep agg2+decode fusion; (c) NEW: fuse gemm2 into agg1's epilogue --
// hrelu rows (fp32, post-relu, in regs) -> 2KB LDS -> 64 threads/node dot
// W2 columns (32KB L2-hot) -> h2b bf16 direct. Deletes gemm2 dispatch + the
// 51MB hrelu round-trip; the 128-FMA tail hides under agg1's ~60% stall.
// Numerics: gemm2 consumes fp32 hrelu (closer to reference than bf16-rounded).
// Falsifier: aggG1 >= 115us -> unfuse gemm2; fused1 >= 100us -> re-diagnose.

#define TPB 256
#define CAP 64
#define BINCAP 220000   // per-bin edge capacity (E/8=200K expected)
#define FILLW 112       // fill blocks per bin

typedef float v2f __attribute__((ext_vector_type(2)));

// ---------------- helpers ----------------

__device__ __forceinline__ unsigned short f2bf(float f) {
    unsigned u = __float_as_uint(f);
    unsigned r = u + 0x7fffu + ((u >> 16) & 1u);  // RNE
    return (unsigned short)(r >> 16);
}
__device__ __forceinline__ float bf_lo(unsigned u) { return __uint_as_float(u << 16); }
__device__ __forceinline__ float bf_hi(unsigned u) { return __uint_as_float(u & 0xffff0000u); }

// ---------------- GEMM body: out[N,C] = A[N,K] @ W[K,C] (+bias) ----------------

template <int K, int C, int TN, bool BIAS, bool INBF, bool OUTBF>
__device__ __forceinline__ void gemm_body(const void* __restrict__ Ap,
                                          const float* __restrict__ W,
                                          const float* __restrict__ bias,
                                          void* __restrict__ outp, int N, int bid,
                                          float* __restrict__ Ws) {
    constexpr int BM  = 128;
    constexpr int TM  = 8;
    constexpr int BK  = 32;
    constexpr int NCT = C / TN;
    static_assert(NCT * (BM / TM) == TPB, "thread layout");

    int tid = threadIdx.x;
    int tc = tid % NCT;
    int tr = tid / NCT;
    int c0 = tc * TN;
    int r0 = bid * BM + tr * TM;

    float acc[TM][TN] = {};

    for (int k0 = 0; k0 < K; k0 += BK) {
        __syncthreads();
        for (int i = tid * 4; i < BK * C; i += TPB * 4)
            *(float4*)&Ws[i] = *(const float4*)&W[k0 * C + i];
        __syncthreads();

        for (int k = 0; k < BK; k += 4) {
            float4 a[TM];
            uint2  au[TM];
#pragma unroll
            for (int i = 0; i < TM; ++i) {
                int r = r0 + i;
                if (r >= N) r = N - 1;
                if (INBF)
                    au[i] = *(const uint2*)((const unsigned short*)Ap + (size_t)r * K + k0 + k);
                else
                    a[i] = *(const float4*)((const float*)Ap + (size_t)r * K + k0 + k);
            }
#pragma unroll
            for (int kk = 0; kk < 4; ++kk) {
                float w[TN];
#pragma unroll
                for (int j = 0; j < TN; j += 4)
                    *(float4*)&w[j] = *(const float4*)&Ws[(k + kk) * C + c0 + j];
#pragma unroll
                for (int i = 0; i < TM; ++i) {
                    float av;
                    if (INBF) {
                        unsigned uu = (kk < 2) ? au[i].x : au[i].y;
                        av = (kk & 1) ? bf_hi(uu) : bf_lo(uu);
                    } else {
                        av = ((const float*)&a[i])[kk];
                    }
#pragma unroll
                    for (int j = 0; j < TN; ++j) acc[i][j] += av * w[j];
                }
            }
        }
    }

#pragma unroll
    for (int i = 0; i < TM; ++i) {
        int r = r0 + i;
        if (r >= N) continue;
        if (BIAS) {
#pragma unroll
            for (int j = 0; j < TN; ++j) acc[i][j] += bias[c0 + j];
        }
        if (OUTBF) {
            unsigned short* ob = (unsigned short*)outp + (size_t)r * C + c0;
            unsigned pk[TN / 2];
#pragma unroll
            for (int j = 0; j < TN; j += 2)
                pk[j / 2] = (unsigned)f2bf(acc[i][j]) | ((unsigned)f2bf(acc[i][j + 1]) << 16);
            if (TN == 8)      *(uint4*)ob = *(uint4*)pk;
            else if (TN == 4) *(uint2*)ob = *(uint2*)pk;
        } else {
            float* of = (float*)outp + (size_t)r * C + c0;
#pragma unroll
            for (int j = 0; j < TN; j += 4)
                *(float4*)&of[j] = *(float4*)&acc[i][j];
        }
    }
}

// ---------------- fused: gemm1 blocks + edge-binning blocks (R8-exact) ----------------

__global__ __launch_bounds__(TPB) void fused1_k(const float* __restrict__ x,
                                                const float* __restrict__ W1,
                                                unsigned* __restrict__ h1b,
                                                const int* __restrict__ src,
                                                const int* __restrict__ dst,
                                                uint2* __restrict__ binBuf,
                                                int* __restrict__ binCnt,
                                                int N, int E, int gb, unsigned M) {
    __shared__ float Ws[32 * 128];
    __shared__ int hist[8], gbase[8], lpos[8];
    if ((int)blockIdx.x < gb) {
        gemm_body<128, 128, 8, false, false, true>(x, W1, nullptr, h1b, N, blockIdx.x, Ws);
    } else {
        int bid = (int)blockIdx.x - gb;
        int tid = (int)threadIdx.x;
        if (tid < 8) { hist[tid] = 0; lpos[tid] = 0; }
        __syncthreads();

        int e0 = (bid * TPB + tid) * 8;
        int ne = E - e0; ne = ne > 8 ? 8 : (ne < 0 ? 0 : ne);
        int ss[8], dd[8], bb8[8];
        if (ne == 8) {
            int4 sa = *(const int4*)&src[e0];
            int4 sb = *(const int4*)&src[e0 + 4];
            int4 da = *(const int4*)&dst[e0];
            int4 db = *(const int4*)&dst[e0 + 4];
            ss[0]=sa.x; ss[1]=sa.y; ss[2]=sa.z; ss[3]=sa.w;
            ss[4]=sb.x; ss[5]=sb.y; ss[6]=sb.z; ss[7]=sb.w;
            dd[0]=da.x; dd[1]=da.y; dd[2]=da.z; dd[3]=da.w;
            dd[4]=db.x; dd[5]=db.y; dd[6]=db.z; dd[7]=db.w;
        } else {
            for (int q = 0; q < ne; ++q) { ss[q] = src[e0 + q]; dd[q] = dst[e0 + q]; }
        }
        for (int q = 0; q < ne; ++q) {
            bb8[q] = (int)(((unsigned long long)(unsigned)dd[q] * M) >> 32);
            atomicAdd(&hist[bb8[q]], 1);
        }
        __syncthreads();
        if (tid < 8) gbase[tid] = atomicAdd(&binCnt[tid], hist[tid]);
        __syncthreads();
        for (int q = 0; q < ne; ++q) {
            int b = bb8[q];
            int p = gbase[b] + atomicAdd(&lpos[b], 1);
            if (p < BINCAP)
                binBuf[(size_t)b * BINCAP + p] = make_uint2((unsigned)ss[q], (unsigned)dd[q]);
        }
    }
}

// ---------------- XCD-affine fill (rank-major bucket, R8-exact) ----------------

__global__ __launch_bounds__(TPB) void fill_k(const uint2* __restrict__ binBuf,
                                              const int* __restrict__ binCnt,
                                              int* __restrict__ cnt,
                                              unsigned* __restrict__ bucket, int N) {
    int bin = (int)blockIdx.x & 7;
    int w   = (int)blockIdx.x >> 3;
    int cb  = binCnt[bin];
    if (cb > BINCAP) cb = BINCAP;
    const uint2* eb = binBuf + (size_t)bin * BINCAP;

    for (int base = w * (TPB * 8); base < cb; base += FILLW * (TPB * 8)) {
        int e0 = base + (int)threadIdx.x * 8;
        if (e0 + 8 <= cb) {
            unsigned s[8], d[8];
#pragma unroll
            for (int q = 0; q < 8; q += 2) {
                uint4 t = *(const uint4*)&eb[e0 + q];
                s[q] = t.x; d[q] = t.y; s[q + 1] = t.z; d[q + 1] = t.w;
            }
            int rr[8];
#pragma unroll
            for (int q = 0; q < 8; ++q) rr[q] = atomicAdd(&cnt[(int)d[q]], 1);
#pragma unroll
            for (int q = 0; q < 8; ++q)
                if (rr[q] < CAP) bucket[(size_t)rr[q] * N + d[q]] = s[q];
        } else {
            int lim = e0 + 8 < cb ? e0 + 8 : cb;
            for (int e = e0; e < lim; ++e) {
                uint2 t = eb[e];
                int r = atomicAdd(&cnt[(int)t.y], 1);
                if (r < CAP) bucket[(size_t)r * N + t.y] = t.x;
            }
        }
    }
}

// ---------------- dinv precompute: dinv[n] = rsqrt(cnt[n]+1) ----------------

__global__ __launch_bounds__(TPB) void dinv_k(const int* __restrict__ cnt,
                                              float* __restrict__ dinv, int N) {
    int i = blockIdx.x * TPB + (int)threadIdx.x;
    if (i < N) dinv[i] = rsqrtf((float)cnt[i] + 1.0f);
}

// ---------------- agg1 + fused gemm2 ----------------
// agg body R8-exact (rank-major bucket, dinv table, batch-8 + prefetch).
// hrelu row (fp32, post-relu) -> 2KB LDS -> 64 threads/node each dot one W2
// column (coalesced 256B/k-step, W2 L2-hot) -> pack bf16 via shfl_down ->
// h2b [N,32] uints. Deletes gemm2 dispatch + 51MB hrelu round-trip.

__global__ __launch_bounds__(TPB) void aggG1_k(const unsigned* __restrict__ h,
                                               const float* __restrict__ dinv,
                                               const int* __restrict__ cnt,
                                               const unsigned* __restrict__ bucket,
                                               const float* __restrict__ b1,
                                               const float* __restrict__ W2,
                                               unsigned* __restrict__ h2b, int N) {
    constexpr int F2 = 64, NPB = TPB / F2;  // 4 nodes/block
    __shared__ float zl[NPB][128];
    int tid = (int)threadIdx.x;
    int ln = tid / F2;
    int f2 = tid % F2;
    int n  = blockIdx.x * NPB + ln;

    if (n < N) {
        int cfull = cnt[n];
        float di = dinv[n];
        const unsigned* hp = h + f2;
        unsigned us = hp[(size_t)n * F2];
        v2f acc;
        acc.x = bf_lo(us) * (di * di);
        acc.y = bf_hi(us) * (di * di);

        int cn = cfull < CAP ? cfull : CAP;
        const unsigned* bp = bucket + n;  // rank-major: plane stride = N

        int nfull = cn & ~7;
        int s[8], sn2[8];
        if (nfull > 0) {
#pragma unroll
            for (int q = 0; q < 8; ++q) s[q] = (int)bp[(size_t)q * N];
        }
        for (int j = 0; j < nfull; ) {
            int jn = j + 8;
            bool more = jn < nfull;
            if (more) {
#pragma unroll
                for (int q = 0; q < 8; ++q) sn2[q] = (int)bp[(size_t)(jn + q) * N];
            }
            unsigned v[8];
            float ds[8];
#pragma unroll
            for (int q = 0; q < 8; ++q) {
                v[q]  = hp[(size_t)s[q] * F2];
                ds[q] = dinv[s[q]];
            }
#pragma unroll
            for (int q = 0; q < 8; ++q) {
                float c = ds[q] * di;
                v2f hv; hv.x = bf_lo(v[q]); hv.y = bf_hi(v[q]);
                acc += hv * c;
            }
            if (more) {
#pragma unroll
                for (int q = 0; q < 8; ++q) s[q] = sn2[q];
            }
            j = jn;
        }
        for (int j = nfull; j < cn; ++j) {
            int sx = (int)bp[(size_t)j * N];
            unsigned v = hp[(size_t)sx * F2];
            float c = dinv[sx] * di;
            acc.x += c * bf_lo(v);
            acc.y += c * bf_hi(v);
        }

        float rx = fmaxf(acc.x + b1[2 * f2], 0.f);
        float ry = fmaxf(acc.y + b1[2 * f2 + 1], 0.f);
        zl[ln][2 * f2]     = rx;
        zl[ln][2 * f2 + 1] = ry;
    }
    __syncthreads();

    // gemm2 tail: node dn = tid/64 (wave-aligned), col c = tid&63
    int dn = tid / 64;
    int c  = tid & 63;
    int nn = blockIdx.x * NPB + dn;
    if (nn < N) {
        float a = 0.f;
        const float* w = W2 + c;
#pragma unroll 8
        for (int k = 0; k < 128; ++k) a += zl[dn][k] * w[(size_t)k * 64];
        float b = __shfl_down(a, 1);
        if ((c & 1) == 0) {
            unsigned pk = (unsigned)f2bf(a) | ((unsigned)f2bf(b) << 16);
            h2b[(size_t)nn * 32 + (c >> 1)] = pk;
        }
    }
}

// ---------------- agg2 + fused decode (R11-exact) ----------------

__global__ __launch_bounds__(TPB) void agg2g_k(const unsigned* __restrict__ h,
                                               const float* __restrict__ dinv,
                                               const int* __restrict__ cnt,
                                               const unsigned* __restrict__ bucket,
                                               const float* __restrict__ bias,
                                               const float* __restrict__ Wd,
                                               const float* __restrict__ bd,
                                               float* __restrict__ z_out,
                                               float* __restrict__ x_recon, int N) {
    constexpr int F2 = 32, NPB = TPB / F2;  // 8 nodes/block
    __shared__ float zl[NPB][64];
    int ln = (int)threadIdx.x / F2;
    int f2 = (int)threadIdx.x % F2;
    int n  = blockIdx.x * NPB + ln;

    if (n < N) {
        int cfull = cnt[n];
        float di = dinv[n];
        const unsigned* hp = h + f2;
        unsigned us = hp[(size_t)n * F2];
        v2f acc;
        acc.x = bf_lo(us) * (di * di);
        acc.y = bf_hi(us) * (di * di);

        int cn = cfull < CAP ? cfull : CAP;
        const unsigned* bp = bucket + n;

        int nfull = cn & ~7;
        int s[8], sn2[8];
        if (nfull > 0) {
#pragma unroll
            for (int q = 0; q < 8; ++q) s[q] = (int)bp[(size_t)q * N];
        }
        for (int j = 0; j < nfull; ) {
            int jn = j + 8;
            bool more = jn < nfull;
            if (more) {
#pragma unroll
                for (int q = 0; q < 8; ++q) sn2[q] = (int)bp[(size_t)(jn + q) * N];
            }
            unsigned v[8];
            float ds[8];
#pragma unroll
            for (int q = 0; q < 8; ++q) {
                v[q]  = hp[(size_t)s[q] * F2];
                ds[q] = dinv[s[q]];
            }
#pragma unroll
            for (int q = 0; q < 8; ++q) {
                float c = ds[q] * di;
                v2f hv; hv.x = bf_lo(v[q]); hv.y = bf_hi(v[q]);
                acc += hv * c;
            }
            if (more) {
#pragma unroll
                for (int q = 0; q < 8; ++q) s[q] = sn2[q];
            }
            j = jn;
        }
        for (int j = nfull; j < cn; ++j) {
            int sx = (int)bp[(size_t)j * N];
            unsigned v = hp[(size_t)sx * F2];
            float c = dinv[sx] * di;
            acc.x += c * bf_lo(v);
            acc.y += c * bf_hi(v);
        }

        float rx = acc.x + bias[2 * f2];
        float ry = acc.y + bias[2 * f2 + 1];
        v2f r; r.x = rx; r.y = ry;
        __builtin_nontemporal_store(r, (v2f*)z_out + (size_t)n * F2 + f2);
        *(v2f*)&zl[ln][2 * f2] = r;
    }
    __syncthreads();

    // decode: thread t -> node t/32, cols (t%32)*4 .. +3
    int dn = (int)threadIdx.x / 32;
    int c0 = ((int)threadIdx.x % 32) * 4;
    int nn = blockIdx.x * NPB + dn;
    if (nn < N) {
        float a0 = bd[c0], a1 = bd[c0 + 1], a2 = bd[c0 + 2], a3 = bd[c0 + 3];
#pragma unroll 4
        for (int k = 0; k < 64; ++k) {
            float zv = zl[dn][k];
            float4 w = *(const float4*)&Wd[k * 128 + c0];
            a0 += zv * w.x; a1 += zv * w.y; a2 += zv * w.z; a3 += zv * w.w;
        }
        float4 o; o.x = a0; o.y = a1; o.z = a2; o.w = a3;
        *(float4*)&x_recon[(size_t)nn * 128 + c0] = o;
    }
}

// ---------------- launch ----------------

extern "C" void kernel_launch(void* const* d_in, const int* in_sizes, int n_in,
                              void* d_out, int out_size, void* d_ws, size_t ws_size,
                              hipStream_t stream) {
    const float* x    = (const float*)d_in[0];
    const int*   eidx = (const int*)d_in[1];
    const float* W1   = (const float*)d_in[2];
    const float* b1   = (const float*)d_in[3];
    const float* W2   = (const float*)d_in[4];
    const float* b2   = (const float*)d_in[5];
    const float* Wd   = (const float*)d_in[6];
    const float* bd   = (const float*)d_in[7];

    const int N = in_sizes[0] / 128;   // 100000
    const int E = in_sizes[1] / 2;     // 1600000
    const int* src = eidx;
    const int* dst = eidx + E;

    size_t off = 0;
    auto alloc = [&](size_t bytes) {
        void* p = (char*)d_ws + off;
        off += (bytes + 255) & ~(size_t)255;
        return p;
    };
    int*      cnt     = (int*)alloc((size_t)N * 4);
    float*    dinv    = (float*)alloc((size_t)N * 4);
    unsigned* bucket  = (unsigned*)alloc((size_t)N * CAP * 4);    // 25.6 MB, rank-major [CAP][N]
    unsigned* h1b     = (unsigned*)alloc((size_t)N * 64 * 4);     // bf16 [N,128]
    unsigned* h2b     = (unsigned*)alloc((size_t)N * 32 * 4);     // bf16 [N,64]
    uint2*    binBuf  = (uint2*)alloc((size_t)8 * BINCAP * 8);    // 14.1 MB
    int*      binCnt  = (int*)alloc(256);
    (void)ws_size;

    float* x_recon = (float*)d_out;                    // [N,128]
    float* z_out   = (float*)d_out + (size_t)N * 128;  // [N,64]

    const int gb = (N + 127) / 128;                 // 782 gemm blocks
    const int bb = (E + TPB * 8 - 1) / (TPB * 8);   // 782 bin blocks
    const unsigned M = (unsigned)((8ULL << 32) / (unsigned)N);  // bin multiplier

    (void)hipMemsetAsync(cnt, 0, (size_t)N * 4, stream);
    (void)hipMemsetAsync(binCnt, 0, 256, stream);

    // fused: gemm1 || edge binning
    fused1_k<<<gb + bb, TPB, 0, stream>>>(x, W1, h1b, src, dst, binBuf, binCnt, N, E, gb, M);
    // XCD-affine count+fill
    fill_k<<<8 * FILLW, TPB, 0, stream>>>(binBuf, binCnt, cnt, bucket, N);
    // dinv table
    dinv_k<<<(N + TPB - 1) / TPB, TPB, 0, stream>>>(cnt, dinv, N);

    // layer 1 aggregation + fused gemm2
    aggG1_k<<<(N + 3) / 4, TPB, 0, stream>>>(h1b, dinv, cnt, bucket, b1, W2, h2b, N);
    // layer 2 aggregation + fused decode
    agg2g_k<<<(N + 7) / 8, TPB, 0, stream>>>(h2b, dinv, cnt, bucket, b2, Wd, bd,
                                             z_out, x_recon, N);
}

// Round 8
// 505.916 us; speedup vs baseline: 1.0637x; 1.0637x over previous
//
#include <hip/hip_runtime.h>
#include <hip/hip_bf16.h>
#include <hip/hip_fp16.h>

// GCN autoencoder, R13:
//   memset(cnt,binCnt) -> fused1{gemm1 || bin->binBuf} -> fill_k(XCD-affine) ->
//   dinv_k -> agg1(R8-exact) -> gemm2(standalone, R8-exact) ->
//   agg2g(agg2 + fused decode)
//
// R12 post-mortem: gemm2-fusion falsifier hit (aggG1 172us). Mechanism
// quantified: tail re-reads 32KB W2 per node -> 100K x 32KB = 3.2GB L1/L2
// traffic ~= 90us at 34.5TB/s L2 -- exactly the 83->172 delta (FETCH flat at
// 225MB: W2 is L2-resident, it's cache-BW not HBM). 4-node/block amortization
// can't pay that; agg2g's decode tail survives because it amortizes Wd over
// 8 nodes and was measured clean in R11+R12.
// R13: revert to R8's measured-best pipeline EXACTLY, keep ONLY the decode
// fusion (two clean rounds). Isolates decode-fusion's value vs the R8=470
// anchor. Predict: agg1 ~83us top, total ~430-445. If >=465, decode fusion
// is worthless -> expose mid-pack kernels next.

#define TPB 256
#define CAP 64
#define BINCAP 220000   // per-bin edge capacity (E/8=200K expected)
#define FILLW 112       // fill blocks per bin

typedef float v2f __attribute__((ext_vector_type(2)));

// ---------------- helpers ----------------

__device__ __forceinline__ unsigned short f2bf(float f) {
    unsigned u = __float_as_uint(f);
    unsigned r = u + 0x7fffu + ((u >> 16) & 1u);  // RNE
    return (unsigned short)(r >> 16);
}
__device__ __forceinline__ float bf_lo(unsigned u) { return __uint_as_float(u << 16); }
__device__ __forceinline__ float bf_hi(unsigned u) { return __uint_as_float(u & 0xffff0000u); }

// ---------------- GEMM body: out[N,C] = A[N,K] @ W[K,C] (+bias) ----------------

template <int K, int C, int TN, bool BIAS, bool INBF, bool OUTBF>
__device__ __forceinline__ void gemm_body(const void* __restrict__ Ap,
                                          const float* __restrict__ W,
                                          const float* __restrict__ bias,
                                          void* __restrict__ outp, int N, int bid,
                                          float* __restrict__ Ws) {
    constexpr int BM  = 128;
    constexpr int TM  = 8;
    constexpr int BK  = 32;
    constexpr int NCT = C / TN;
    static_assert(NCT * (BM / TM) == TPB, "thread layout");

    int tid = threadIdx.x;
    int tc = tid % NCT;
    int tr = tid / NCT;
    int c0 = tc * TN;
    int r0 = bid * BM + tr * TM;

    float acc[TM][TN] = {};

    for (int k0 = 0; k0 < K; k0 += BK) {
        __syncthreads();
        for (int i = tid * 4; i < BK * C; i += TPB * 4)
            *(float4*)&Ws[i] = *(const float4*)&W[k0 * C + i];
        __syncthreads();

        for (int k = 0; k < BK; k += 4) {
            float4 a[TM];
            uint2  au[TM];
#pragma unroll
            for (int i = 0; i < TM; ++i) {
                int r = r0 + i;
                if (r >= N) r = N - 1;
                if (INBF)
                    au[i] = *(const uint2*)((const unsigned short*)Ap + (size_t)r * K + k0 + k);
                else
                    a[i] = *(const float4*)((const float*)Ap + (size_t)r * K + k0 + k);
            }
#pragma unroll
            for (int kk = 0; kk < 4; ++kk) {
                float w[TN];
#pragma unroll
                for (int j = 0; j < TN; j += 4)
                    *(float4*)&w[j] = *(const float4*)&Ws[(k + kk) * C + c0 + j];
#pragma unroll
                for (int i = 0; i < TM; ++i) {
                    float av;
                    if (INBF) {
                        unsigned uu = (kk < 2) ? au[i].x : au[i].y;
                        av = (kk & 1) ? bf_hi(uu) : bf_lo(uu);
                    } else {
                        av = ((const float*)&a[i])[kk];
                    }
#pragma unroll
                    for (int j = 0; j < TN; ++j) acc[i][j] += av * w[j];
                }
            }
        }
    }

#pragma unroll
    for (int i = 0; i < TM; ++i) {
        int r = r0 + i;
        if (r >= N) continue;
        if (BIAS) {
#pragma unroll
            for (int j = 0; j < TN; ++j) acc[i][j] += bias[c0 + j];
        }
        if (OUTBF) {
            unsigned short* ob = (unsigned short*)outp + (size_t)r * C + c0;
            unsigned pk[TN / 2];
#pragma unroll
            for (int j = 0; j < TN; j += 2)
                pk[j / 2] = (unsigned)f2bf(acc[i][j]) | ((unsigned)f2bf(acc[i][j + 1]) << 16);
            if (TN == 8)      *(uint4*)ob = *(uint4*)pk;
            else if (TN == 4) *(uint2*)ob = *(uint2*)pk;
        } else {
            float* of = (float*)outp + (size_t)r * C + c0;
#pragma unroll
            for (int j = 0; j < TN; j += 4)
                *(float4*)&of[j] = *(float4*)&acc[i][j];
        }
    }
}

// standalone GEMM kernel (layer 2)
template <int K, int C, int TN, bool BIAS, bool INBF, bool OUTBF>
__global__ __launch_bounds__(TPB) void gemm_k(const void* __restrict__ Ap,
                                              const float* __restrict__ W,
                                              const float* __restrict__ bias,
                                              void* __restrict__ outp, int N) {
    __shared__ float Ws[32 * C];
    gemm_body<K, C, TN, BIAS, INBF, OUTBF>(Ap, W, bias, outp, N, blockIdx.x, Ws);
}

// ---------------- fused: gemm1 blocks + edge-binning blocks (R8-exact) ----------------

__global__ __launch_bounds__(TPB) void fused1_k(const float* __restrict__ x,
                                                const float* __restrict__ W1,
                                                unsigned* __restrict__ h1b,
                                                const int* __restrict__ src,
                                                const int* __restrict__ dst,
                                                uint2* __restrict__ binBuf,
                                                int* __restrict__ binCnt,
                                                int N, int E, int gb, unsigned M) {
    __shared__ float Ws[32 * 128];
    __shared__ int hist[8], gbase[8], lpos[8];
    if ((int)blockIdx.x < gb) {
        gemm_body<128, 128, 8, false, false, true>(x, W1, nullptr, h1b, N, blockIdx.x, Ws);
    } else {
        int bid = (int)blockIdx.x - gb;
        int tid = (int)threadIdx.x;
        if (tid < 8) { hist[tid] = 0; lpos[tid] = 0; }
        __syncthreads();

        int e0 = (bid * TPB + tid) * 8;
        int ne = E - e0; ne = ne > 8 ? 8 : (ne < 0 ? 0 : ne);
        int ss[8], dd[8], bb8[8];
        if (ne == 8) {
            int4 sa = *(const int4*)&src[e0];
            int4 sb = *(const int4*)&src[e0 + 4];
            int4 da = *(const int4*)&dst[e0];
            int4 db = *(const int4*)&dst[e0 + 4];
            ss[0]=sa.x; ss[1]=sa.y; ss[2]=sa.z; ss[3]=sa.w;
            ss[4]=sb.x; ss[5]=sb.y; ss[6]=sb.z; ss[7]=sb.w;
            dd[0]=da.x; dd[1]=da.y; dd[2]=da.z; dd[3]=da.w;
            dd[4]=db.x; dd[5]=db.y; dd[6]=db.z; dd[7]=db.w;
        } else {
            for (int q = 0; q < ne; ++q) { ss[q] = src[e0 + q]; dd[q] = dst[e0 + q]; }
        }
        for (int q = 0; q < ne; ++q) {
            bb8[q] = (int)(((unsigned long long)(unsigned)dd[q] * M) >> 32);
            atomicAdd(&hist[bb8[q]], 1);
        }
        __syncthreads();
        if (tid < 8) gbase[tid] = atomicAdd(&binCnt[tid], hist[tid]);
        __syncthreads();
        for (int q = 0; q < ne; ++q) {
            int b = bb8[q];
            int p = gbase[b] + atomicAdd(&lpos[b], 1);
            if (p < BINCAP)
                binBuf[(size_t)b * BINCAP + p] = make_uint2((unsigned)ss[q], (unsigned)dd[q]);
        }
    }
}

// ---------------- XCD-affine fill (rank-major bucket, R8-exact) ----------------

__global__ __launch_bounds__(TPB) void fill_k(const uint2* __restrict__ binBuf,
                                              const int* __restrict__ binCnt,
                                              int* __restrict__ cnt,
                                              unsigned* __restrict__ bucket, int N) {
    int bin = (int)blockIdx.x & 7;
    int w   = (int)blockIdx.x >> 3;
    int cb  = binCnt[bin];
    if (cb > BINCAP) cb = BINCAP;
    const uint2* eb = binBuf + (size_t)bin * BINCAP;

    for (int base = w * (TPB * 8); base < cb; base += FILLW * (TPB * 8)) {
        int e0 = base + (int)threadIdx.x * 8;
        if (e0 + 8 <= cb) {
            unsigned s[8], d[8];
#pragma unroll
            for (int q = 0; q < 8; q += 2) {
                uint4 t = *(const uint4*)&eb[e0 + q];
                s[q] = t.x; d[q] = t.y; s[q + 1] = t.z; d[q + 1] = t.w;
            }
            int rr[8];
#pragma unroll
            for (int q = 0; q < 8; ++q) rr[q] = atomicAdd(&cnt[(int)d[q]], 1);
#pragma unroll
            for (int q = 0; q < 8; ++q)
                if (rr[q] < CAP) bucket[(size_t)rr[q] * N + d[q]] = s[q];
        } else {
            int lim = e0 + 8 < cb ? e0 + 8 : cb;
            for (int e = e0; e < lim; ++e) {
                uint2 t = eb[e];
                int r = atomicAdd(&cnt[(int)t.y], 1);
                if (r < CAP) bucket[(size_t)r * N + t.y] = t.x;
            }
        }
    }
}

// ---------------- dinv precompute: dinv[n] = rsqrt(cnt[n]+1) ----------------

__global__ __launch_bounds__(TPB) void dinv_k(const int* __restrict__ cnt,
                                              float* __restrict__ dinv, int N) {
    int i = blockIdx.x * TPB + (int)threadIdx.x;
    if (i < N) dinv[i] = rsqrtf((float)cnt[i] + 1.0f);
}

// ---------------- bucket gather aggregation (R8-exact) ----------------

template <int F2, bool RELU, bool OUTBF>
__global__ __launch_bounds__(TPB) void agg_k(const unsigned* __restrict__ h,
                                             const float* __restrict__ dinv,
                                             const int* __restrict__ cnt,
                                             const unsigned* __restrict__ bucket,
                                             const float* __restrict__ bias,
                                             void* __restrict__ outp, int N) {
    constexpr int NPB = TPB / F2;
    int ln = threadIdx.x / F2;
    int f2 = threadIdx.x % F2;
    int n  = blockIdx.x * NPB + ln;
    if (n >= N) return;

    int cfull = cnt[n];
    float di = dinv[n];
    const unsigned* hp = h + f2;
    unsigned us = hp[(size_t)n * F2];
    v2f acc;
    acc.x = bf_lo(us) * (di * di);
    acc.y = bf_hi(us) * (di * di);

    int cn = cfull < CAP ? cfull : CAP;
    const unsigned* bp = bucket + n;  // rank-major: plane stride = N

    int nfull = cn & ~7;
    int s[8], sn2[8];
    if (nfull > 0) {
#pragma unroll
        for (int q = 0; q < 8; ++q) s[q] = (int)bp[(size_t)q * N];
    }
    for (int j = 0; j < nfull; ) {
        int jn = j + 8;
        bool more = jn < nfull;
        if (more) {
#pragma unroll
            for (int q = 0; q < 8; ++q) sn2[q] = (int)bp[(size_t)(jn + q) * N];
        }
        unsigned v[8];
        float ds[8];
#pragma unroll
        for (int q = 0; q < 8; ++q) {
            v[q]  = hp[(size_t)s[q] * F2];
            ds[q] = dinv[s[q]];
        }
#pragma unroll
        for (int q = 0; q < 8; ++q) {
            float c = ds[q] * di;
            v2f hv; hv.x = bf_lo(v[q]); hv.y = bf_hi(v[q]);
            acc += hv * c;
        }
        if (more) {
#pragma unroll
            for (int q = 0; q < 8; ++q) s[q] = sn2[q];
        }
        j = jn;
    }
    for (int j = nfull; j < cn; ++j) {
        int sx = (int)bp[(size_t)j * N];
        unsigned v = hp[(size_t)sx * F2];
        float c = dinv[sx] * di;
        acc.x += c * bf_lo(v);
        acc.y += c * bf_hi(v);
    }

    float rx = acc.x + bias[2 * f2];
    float ry = acc.y + bias[2 * f2 + 1];
    if (RELU) { rx = fmaxf(rx, 0.f); ry = fmaxf(ry, 0.f); }
    if (OUTBF) {
        unsigned pk = (unsigned)f2bf(rx) | ((unsigned)f2bf(ry) << 16);
        ((unsigned*)outp)[(size_t)n * F2 + f2] = pk;
    } else {
        v2f r; r.x = rx; r.y = ry;
        __builtin_nontemporal_store(r, (v2f*)outp + (size_t)n * F2 + f2);
    }
}

// ---------------- agg2 + fused decode (R11-exact, measured clean 2 rounds) ----------------

__global__ __launch_bounds__(TPB) void agg2g_k(const unsigned* __restrict__ h,
                                               const float* __restrict__ dinv,
                                               const int* __restrict__ cnt,
                                               const unsigned* __restrict__ bucket,
                                               const float* __restrict__ bias,
                                               const float* __restrict__ Wd,
                                               const float* __restrict__ bd,
                                               float* __restrict__ z_out,
                                               float* __restrict__ x_recon, int N) {
    constexpr int F2 = 32, NPB = TPB / F2;  // 8 nodes/block
    __shared__ float zl[NPB][64];
    int ln = (int)threadIdx.x / F2;
    int f2 = (int)threadIdx.x % F2;
    int n  = blockIdx.x * NPB + ln;

    if (n < N) {
        int cfull = cnt[n];
        float di = dinv[n];
        const unsigned* hp = h + f2;
        unsigned us = hp[(size_t)n * F2];
        v2f acc;
        acc.x = bf_lo(us) * (di * di);
        acc.y = bf_hi(us) * (di * di);

        int cn = cfull < CAP ? cfull : CAP;
        const unsigned* bp = bucket + n;

        int nfull = cn & ~7;
        int s[8], sn2[8];
        if (nfull > 0) {
#pragma unroll
            for (int q = 0; q < 8; ++q) s[q] = (int)bp[(size_t)q * N];
        }
        for (int j = 0; j < nfull; ) {
            int jn = j + 8;
            bool more = jn < nfull;
            if (more) {
#pragma unroll
                for (int q = 0; q < 8; ++q) sn2[q] = (int)bp[(size_t)(jn + q) * N];
            }
            unsigned v[8];
            float ds[8];
#pragma unroll
            for (int q = 0; q < 8; ++q) {
                v[q]  = hp[(size_t)s[q] * F2];
                ds[q] = dinv[s[q]];
            }
#pragma unroll
            for (int q = 0; q < 8; ++q) {
                float c = ds[q] * di;
                v2f hv; hv.x = bf_lo(v[q]); hv.y = bf_hi(v[q]);
                acc += hv * c;
            }
            if (more) {
#pragma unroll
                for (int q = 0; q < 8; ++q) s[q] = sn2[q];
            }
            j = jn;
        }
        for (int j = nfull; j < cn; ++j) {
            int sx = (int)bp[(size_t)j * N];
            unsigned v = hp[(size_t)sx * F2];
            float c = dinv[sx] * di;
            acc.x += c * bf_lo(v);
            acc.y += c * bf_hi(v);
        }

        float rx = acc.x + bias[2 * f2];
        float ry = acc.y + bias[2 * f2 + 1];
        v2f r; r.x = rx; r.y = ry;
        __builtin_nontemporal_store(r, (v2f*)z_out + (size_t)n * F2 + f2);
        *(v2f*)&zl[ln][2 * f2] = r;
    }
    __syncthreads();

    // decode: thread t -> node t/32, cols (t%32)*4 .. +3
    int dn = (int)threadIdx.x / 32;
    int c0 = ((int)threadIdx.x % 32) * 4;
    int nn = blockIdx.x * NPB + dn;
    if (nn < N) {
        float a0 = bd[c0], a1 = bd[c0 + 1], a2 = bd[c0 + 2], a3 = bd[c0 + 3];
#pragma unroll 4
        for (int k = 0; k < 64; ++k) {
            float zv = zl[dn][k];
            float4 w = *(const float4*)&Wd[k * 128 + c0];
            a0 += zv * w.x; a1 += zv * w.y; a2 += zv * w.z; a3 += zv * w.w;
        }
        float4 o; o.x = a0; o.y = a1; o.z = a2; o.w = a3;
        *(float4*)&x_recon[(size_t)nn * 128 + c0] = o;
    }
}

// ---------------- launch ----------------

extern "C" void kernel_launch(void* const* d_in, const int* in_sizes, int n_in,
                              void* d_out, int out_size, void* d_ws, size_t ws_size,
                              hipStream_t stream) {
    const float* x    = (const float*)d_in[0];
    const int*   eidx = (const int*)d_in[1];
    const float* W1   = (const float*)d_in[2];
    const float* b1   = (const float*)d_in[3];
    const float* W2   = (const float*)d_in[4];
    const float* b2   = (const float*)d_in[5];
    const float* Wd   = (const float*)d_in[6];
    const float* bd   = (const float*)d_in[7];

    const int N = in_sizes[0] / 128;   // 100000
    const int E = in_sizes[1] / 2;     // 1600000
    const int* src = eidx;
    const int* dst = eidx + E;

    size_t off = 0;
    auto alloc = [&](size_t bytes) {
        void* p = (char*)d_ws + off;
        off += (bytes + 255) & ~(size_t)255;
        return p;
    };
    int*      cnt     = (int*)alloc((size_t)N * 4);
    float*    dinv    = (float*)alloc((size_t)N * 4);
    unsigned* bucket  = (unsigned*)alloc((size_t)N * CAP * 4);  // 25.6 MB, rank-major [CAP][N]
    unsigned* h1b     = (unsigned*)alloc((size_t)N * 64 * 4);   // bf16 [N,128]
    unsigned* h2b     = (unsigned*)alloc((size_t)N * 32 * 4);   // bf16 [N,64]
    unsigned* hrelu_b = (unsigned*)alloc((size_t)N * 64 * 4);   // bf16 [N,128]
    int*      binCnt  = (int*)alloc(256);
    // binBuf (8*BINCAP*8B = 14.1MB) overlays hrelu_b: dead before agg1 writes it.
    uint2*    binBuf  = (uint2*)hrelu_b;
    (void)ws_size;

    float* x_recon = (float*)d_out;                    // [N,128]
    float* z_out   = (float*)d_out + (size_t)N * 128;  // [N,64]

    const int gb = (N + 127) / 128;                 // 782 gemm blocks
    const int bb = (E + TPB * 8 - 1) / (TPB * 8);   // 782 bin blocks
    const unsigned M = (unsigned)((8ULL << 32) / (unsigned)N);  // bin multiplier

    (void)hipMemsetAsync(cnt, 0, (size_t)N * 4, stream);
    (void)hipMemsetAsync(binCnt, 0, 256, stream);

    // fused: gemm1 || edge binning
    fused1_k<<<gb + bb, TPB, 0, stream>>>(x, W1, h1b, src, dst, binBuf, binCnt, N, E, gb, M);
    // XCD-affine count+fill
    fill_k<<<8 * FILLW, TPB, 0, stream>>>(binBuf, binCnt, cnt, bucket, N);
    // dinv table
    dinv_k<<<(N + TPB - 1) / TPB, TPB, 0, stream>>>(cnt, dinv, N);

    // layer 1 aggregation (R8-exact)
    agg_k<64, true, true><<<(N + 3) / 4, TPB, 0, stream>>>(h1b, dinv, cnt, bucket, b1, hrelu_b, N);
    // layer 2 gemm (standalone, R8-exact)
    gemm_k<128, 64, 4, false, true, true><<<gb, TPB, 0, stream>>>(hrelu_b, W2, nullptr, h2b, N);
    // layer 2 aggregation + fused decode
    agg2g_k<<<(N + 7) / 8, TPB, 0, stream>>>(h2b, dinv, cnt, bucket, b2, Wd, bd,
                                             z_out, x_recon, N);
}

// Round 9
// 463.802 us; speedup vs baseline: 1.1603x; 1.0908x over previous
//
#include <hip/hip_runtime.h>
#include <hip/hip_bf16.h>
#include <hip/hip_fp16.h>

// GCN autoencoder, R14:
//   memset -> bin_k -> fusedGF{gemm1 || fill(XCD-affine)} -> dinv_k ->
//   agg1(R8-exact) -> gemm2(R8-exact) -> agg2(R8-exact) -> gemm3(R8-exact)
//
// R13 post-mortem: the bench top-5 only ever shows THE slowest kernel --
// "agg2g clean" was an artifact of being #2 behind fused1/aggG1. Unmasked:
// agg2g=139us, i.e. decode fusion COSTS ~35us vs standalone agg2+gemm3
// (~103us in R8): the fused tail re-issues 256KB of Wd loads per block with
// no register blocking and serializes behind the gather's __syncthreads.
// Lesson: don't fuse GEMM tails into gather kernels; the tiled standalone
// GEMMs win.
// R14: R8 anchor (470us, every component measured-best) + ONE change:
// bin first (standalone ~30us), then co-schedule {gemm1 || fill} in one
// dispatch -- in R8 fill waited on gemm1 despite needing only the bin arm.
// VALU-bound gemm1 blocks and latency-bound fill blocks interleave on CUs
// (same co-scheduling that worked in R7/R8). fill bin = absolute bid&7 keeps
// XCD affinity; (bin,w) stays bijective.
// Predict: top = agg1 ~83us; fusedGF ~85-95; total ~425-440.
// Falsifier: fusedGF>=130 -> contention, revert sequential.

#define TPB 256
#define CAP 64
#define BINCAP 220000   // per-bin edge capacity (E/8=200K expected)
#define FILLW 112       // fill blocks per bin

typedef float v2f __attribute__((ext_vector_type(2)));

// ---------------- helpers ----------------

__device__ __forceinline__ unsigned short f2bf(float f) {
    unsigned u = __float_as_uint(f);
    unsigned r = u + 0x7fffu + ((u >> 16) & 1u);  // RNE
    return (unsigned short)(r >> 16);
}
__device__ __forceinline__ float bf_lo(unsigned u) { return __uint_as_float(u << 16); }
__device__ __forceinline__ float bf_hi(unsigned u) { return __uint_as_float(u & 0xffff0000u); }

// ---------------- GEMM body: out[N,C] = A[N,K] @ W[K,C] (+bias) ----------------

template <int K, int C, int TN, bool BIAS, bool INBF, bool OUTBF>
__device__ __forceinline__ void gemm_body(const void* __restrict__ Ap,
                                          const float* __restrict__ W,
                                          const float* __restrict__ bias,
                                          void* __restrict__ outp, int N, int bid,
                                          float* __restrict__ Ws) {
    constexpr int BM  = 128;
    constexpr int TM  = 8;
    constexpr int BK  = 32;
    constexpr int NCT = C / TN;
    static_assert(NCT * (BM / TM) == TPB, "thread layout");

    int tid = threadIdx.x;
    int tc = tid % NCT;
    int tr = tid / NCT;
    int c0 = tc * TN;
    int r0 = bid * BM + tr * TM;

    float acc[TM][TN] = {};

    for (int k0 = 0; k0 < K; k0 += BK) {
        __syncthreads();
        for (int i = tid * 4; i < BK * C; i += TPB * 4)
            *(float4*)&Ws[i] = *(const float4*)&W[k0 * C + i];
        __syncthreads();

        for (int k = 0; k < BK; k += 4) {
            float4 a[TM];
            uint2  au[TM];
#pragma unroll
            for (int i = 0; i < TM; ++i) {
                int r = r0 + i;
                if (r >= N) r = N - 1;
                if (INBF)
                    au[i] = *(const uint2*)((const unsigned short*)Ap + (size_t)r * K + k0 + k);
                else
                    a[i] = *(const float4*)((const float*)Ap + (size_t)r * K + k0 + k);
            }
#pragma unroll
            for (int kk = 0; kk < 4; ++kk) {
                float w[TN];
#pragma unroll
                for (int j = 0; j < TN; j += 4)
                    *(float4*)&w[j] = *(const float4*)&Ws[(k + kk) * C + c0 + j];
#pragma unroll
                for (int i = 0; i < TM; ++i) {
                    float av;
                    if (INBF) {
                        unsigned uu = (kk < 2) ? au[i].x : au[i].y;
                        av = (kk & 1) ? bf_hi(uu) : bf_lo(uu);
                    } else {
                        av = ((const float*)&a[i])[kk];
                    }
#pragma unroll
                    for (int j = 0; j < TN; ++j) acc[i][j] += av * w[j];
                }
            }
        }
    }

#pragma unroll
    for (int i = 0; i < TM; ++i) {
        int r = r0 + i;
        if (r >= N) continue;
        if (BIAS) {
#pragma unroll
            for (int j = 0; j < TN; ++j) acc[i][j] += bias[c0 + j];
        }
        if (OUTBF) {
            unsigned short* ob = (unsigned short*)outp + (size_t)r * C + c0;
            unsigned pk[TN / 2];
#pragma unroll
            for (int j = 0; j < TN; j += 2)
                pk[j / 2] = (unsigned)f2bf(acc[i][j]) | ((unsigned)f2bf(acc[i][j + 1]) << 16);
            if (TN == 8)      *(uint4*)ob = *(uint4*)pk;
            else if (TN == 4) *(uint2*)ob = *(uint2*)pk;
        } else {
            float* of = (float*)outp + (size_t)r * C + c0;
#pragma unroll
            for (int j = 0; j < TN; j += 4)
                *(float4*)&of[j] = *(float4*)&acc[i][j];
        }
    }
}

// standalone GEMM kernel (layers 2, 3)
template <int K, int C, int TN, bool BIAS, bool INBF, bool OUTBF>
__global__ __launch_bounds__(TPB) void gemm_k(const void* __restrict__ Ap,
                                              const float* __restrict__ W,
                                              const float* __restrict__ bias,
                                              void* __restrict__ outp, int N) {
    __shared__ float Ws[32 * C];
    gemm_body<K, C, TN, BIAS, INBF, OUTBF>(Ap, W, bias, outp, N, blockIdx.x, Ws);
}

// ---------------- standalone edge binning (R8's bin arm) ----------------

__global__ __launch_bounds__(TPB) void bin_k(const int* __restrict__ src,
                                             const int* __restrict__ dst,
                                             uint2* __restrict__ binBuf,
                                             int* __restrict__ binCnt,
                                             int E, unsigned M) {
    __shared__ int hist[8], gbase[8], lpos[8];
    int bid = (int)blockIdx.x;
    int tid = (int)threadIdx.x;
    if (tid < 8) { hist[tid] = 0; lpos[tid] = 0; }
    __syncthreads();

    int e0 = (bid * TPB + tid) * 8;
    int ne = E - e0; ne = ne > 8 ? 8 : (ne < 0 ? 0 : ne);
    int ss[8], dd[8], bb8[8];
    if (ne == 8) {
        int4 sa = *(const int4*)&src[e0];
        int4 sb = *(const int4*)&src[e0 + 4];
        int4 da = *(const int4*)&dst[e0];
        int4 db = *(const int4*)&dst[e0 + 4];
        ss[0]=sa.x; ss[1]=sa.y; ss[2]=sa.z; ss[3]=sa.w;
        ss[4]=sb.x; ss[5]=sb.y; ss[6]=sb.z; ss[7]=sb.w;
        dd[0]=da.x; dd[1]=da.y; dd[2]=da.z; dd[3]=da.w;
        dd[4]=db.x; dd[5]=db.y; dd[6]=db.z; dd[7]=db.w;
    } else {
        for (int q = 0; q < ne; ++q) { ss[q] = src[e0 + q]; dd[q] = dst[e0 + q]; }
    }
    for (int q = 0; q < ne; ++q) {
        bb8[q] = (int)(((unsigned long long)(unsigned)dd[q] * M) >> 32);
        atomicAdd(&hist[bb8[q]], 1);
    }
    __syncthreads();
    if (tid < 8) gbase[tid] = atomicAdd(&binCnt[tid], hist[tid]);
    __syncthreads();
    for (int q = 0; q < ne; ++q) {
        int b = bb8[q];
        int p = gbase[b] + atomicAdd(&lpos[b], 1);
        if (p < BINCAP)
            binBuf[(size_t)b * BINCAP + p] = make_uint2((unsigned)ss[q], (unsigned)dd[q]);
    }
}

// ---------------- fused: gemm1 blocks || XCD-affine fill blocks ----------------
// fill bin = ABSOLUTE blockIdx.x & 7 (round-robin block->XCD), w = fid>>3:
// within each 8 consecutive absolute bids all residues appear once ->
// (bin,w) bijective over [0,8)x[0,FILLW). gemm1 (VALU-bound) and fill
// (latency/atomic-bound) interleave on the CUs.

__global__ __launch_bounds__(TPB) void fusedGF_k(const float* __restrict__ x,
                                                 const float* __restrict__ W1,
                                                 unsigned* __restrict__ h1b,
                                                 const uint2* __restrict__ binBuf,
                                                 const int* __restrict__ binCnt,
                                                 int* __restrict__ cnt,
                                                 unsigned* __restrict__ bucket,
                                                 int N, int gb) {
    __shared__ float Ws[32 * 128];
    int bid = (int)blockIdx.x;
    if (bid < gb) {
        gemm_body<128, 128, 8, false, false, true>(x, W1, nullptr, h1b, N, bid, Ws);
    } else {
        int fid = bid - gb;
        int bin = bid & 7;          // absolute residue = XCD id
        int w   = fid >> 3;
        int cb  = binCnt[bin];
        if (cb > BINCAP) cb = BINCAP;
        const uint2* eb = binBuf + (size_t)bin * BINCAP;

        for (int base = w * (TPB * 8); base < cb; base += FILLW * (TPB * 8)) {
            int e0 = base + (int)threadIdx.x * 8;
            if (e0 + 8 <= cb) {
                unsigned s[8], d[8];
#pragma unroll
                for (int q = 0; q < 8; q += 2) {
                    uint4 t = *(const uint4*)&eb[e0 + q];
                    s[q] = t.x; d[q] = t.y; s[q + 1] = t.z; d[q + 1] = t.w;
                }
                int rr[8];
#pragma unroll
                for (int q = 0; q < 8; ++q) rr[q] = atomicAdd(&cnt[(int)d[q]], 1);
#pragma unroll
                for (int q = 0; q < 8; ++q)
                    if (rr[q] < CAP) bucket[(size_t)rr[q] * N + d[q]] = s[q];
            } else {
                int lim = e0 + 8 < cb ? e0 + 8 : cb;
                for (int e = e0; e < lim; ++e) {
                    uint2 t = eb[e];
                    int r = atomicAdd(&cnt[(int)t.y], 1);
                    if (r < CAP) bucket[(size_t)r * N + t.y] = t.x;
                }
            }
        }
    }
}

// ---------------- dinv precompute: dinv[n] = rsqrt(cnt[n]+1) ----------------

__global__ __launch_bounds__(TPB) void dinv_k(const int* __restrict__ cnt,
                                              float* __restrict__ dinv, int N) {
    int i = blockIdx.x * TPB + (int)threadIdx.x;
    if (i < N) dinv[i] = rsqrtf((float)cnt[i] + 1.0f);
}

// ---------------- bucket gather aggregation (R8-exact) ----------------

template <int F2, bool RELU, bool OUTBF>
__global__ __launch_bounds__(TPB) void agg_k(const unsigned* __restrict__ h,
                                             const float* __restrict__ dinv,
                                             const int* __restrict__ cnt,
                                             const unsigned* __restrict__ bucket,
                                             const float* __restrict__ bias,
                                             void* __restrict__ outp, int N) {
    constexpr int NPB = TPB / F2;
    int ln = threadIdx.x / F2;
    int f2 = threadIdx.x % F2;
    int n  = blockIdx.x * NPB + ln;
    if (n >= N) return;

    int cfull = cnt[n];
    float di = dinv[n];
    const unsigned* hp = h + f2;
    unsigned us = hp[(size_t)n * F2];
    v2f acc;
    acc.x = bf_lo(us) * (di * di);
    acc.y = bf_hi(us) * (di * di);

    int cn = cfull < CAP ? cfull : CAP;
    const unsigned* bp = bucket + n;  // rank-major: plane stride = N

    int nfull = cn & ~7;
    int s[8], sn2[8];
    if (nfull > 0) {
#pragma unroll
        for (int q = 0; q < 8; ++q) s[q] = (int)bp[(size_t)q * N];
    }
    for (int j = 0; j < nfull; ) {
        int jn = j + 8;
        bool more = jn < nfull;
        if (more) {
#pragma unroll
            for (int q = 0; q < 8; ++q) sn2[q] = (int)bp[(size_t)(jn + q) * N];
        }
        unsigned v[8];
        float ds[8];
#pragma unroll
        for (int q = 0; q < 8; ++q) {
            v[q]  = hp[(size_t)s[q] * F2];
            ds[q] = dinv[s[q]];
        }
#pragma unroll
        for (int q = 0; q < 8; ++q) {
            float c = ds[q] * di;
            v2f hv; hv.x = bf_lo(v[q]); hv.y = bf_hi(v[q]);
            acc += hv * c;
        }
        if (more) {
#pragma unroll
            for (int q = 0; q < 8; ++q) s[q] = sn2[q];
        }
        j = jn;
    }
    for (int j = nfull; j < cn; ++j) {
        int sx = (int)bp[(size_t)j * N];
        unsigned v = hp[(size_t)sx * F2];
        float c = dinv[sx] * di;
        acc.x += c * bf_lo(v);
        acc.y += c * bf_hi(v);
    }

    float rx = acc.x + bias[2 * f2];
    float ry = acc.y + bias[2 * f2 + 1];
    if (RELU) { rx = fmaxf(rx, 0.f); ry = fmaxf(ry, 0.f); }
    if (OUTBF) {
        unsigned pk = (unsigned)f2bf(rx) | ((unsigned)f2bf(ry) << 16);
        ((unsigned*)outp)[(size_t)n * F2 + f2] = pk;
    } else {
        v2f r; r.x = rx; r.y = ry;
        __builtin_nontemporal_store(r, (v2f*)outp + (size_t)n * F2 + f2);
    }
}

// ---------------- launch ----------------

extern "C" void kernel_launch(void* const* d_in, const int* in_sizes, int n_in,
                              void* d_out, int out_size, void* d_ws, size_t ws_size,
                              hipStream_t stream) {
    const float* x    = (const float*)d_in[0];
    const int*   eidx = (const int*)d_in[1];
    const float* W1   = (const float*)d_in[2];
    const float* b1   = (const float*)d_in[3];
    const float* W2   = (const float*)d_in[4];
    const float* b2   = (const float*)d_in[5];
    const float* Wd   = (const float*)d_in[6];
    const float* bd   = (const float*)d_in[7];

    const int N = in_sizes[0] / 128;   // 100000
    const int E = in_sizes[1] / 2;     // 1600000
    const int* src = eidx;
    const int* dst = eidx + E;

    size_t off = 0;
    auto alloc = [&](size_t bytes) {
        void* p = (char*)d_ws + off;
        off += (bytes + 255) & ~(size_t)255;
        return p;
    };
    int*      cnt     = (int*)alloc((size_t)N * 4);
    float*    dinv    = (float*)alloc((size_t)N * 4);
    unsigned* bucket  = (unsigned*)alloc((size_t)N * CAP * 4);  // 25.6 MB, rank-major [CAP][N]
    unsigned* h1b     = (unsigned*)alloc((size_t)N * 64 * 4);   // bf16 [N,128]
    unsigned* h2b     = (unsigned*)alloc((size_t)N * 32 * 4);   // bf16 [N,64]
    unsigned* hrelu_b = (unsigned*)alloc((size_t)N * 64 * 4);   // bf16 [N,128]
    int*      binCnt  = (int*)alloc(256);
    // binBuf (8*BINCAP*8B = 14.1MB) overlays hrelu_b: consumed by fusedGF's
    // fill arm, which completes before agg1 writes hrelu_b.
    uint2*    binBuf  = (uint2*)hrelu_b;
    (void)ws_size;

    float* x_recon = (float*)d_out;                    // [N,128]
    float* z_out   = (float*)d_out + (size_t)N * 128;  // [N,64]

    const int gb = (N + 127) / 128;                 // 782 gemm blocks
    const int bb = (E + TPB * 8 - 1) / (TPB * 8);   // 782 bin blocks
    const unsigned M = (unsigned)((8ULL << 32) / (unsigned)N);  // bin multiplier

    (void)hipMemsetAsync(cnt, 0, (size_t)N * 4, stream);
    (void)hipMemsetAsync(binCnt, 0, 256, stream);

    // edge binning (fast, standalone)
    bin_k<<<bb, TPB, 0, stream>>>(src, dst, binBuf, binCnt, E, M);
    // gemm1 || XCD-affine count+fill (co-scheduled)
    fusedGF_k<<<gb + 8 * FILLW, TPB, 0, stream>>>(x, W1, h1b, binBuf, binCnt,
                                                  cnt, bucket, N, gb);
    // dinv table
    dinv_k<<<(N + TPB - 1) / TPB, TPB, 0, stream>>>(cnt, dinv, N);

    // layer 1 aggregation (R8-exact)
    agg_k<64, true, true><<<(N + 3) / 4, TPB, 0, stream>>>(h1b, dinv, cnt, bucket, b1, hrelu_b, N);
    // layer 2 (R8-exact)
    gemm_k<128, 64, 4, false, true, true><<<gb, TPB, 0, stream>>>(hrelu_b, W2, nullptr, h2b, N);
    agg_k<32, false, false><<<(N + 7) / 8, TPB, 0, stream>>>(h2b, dinv, cnt, bucket, b2, z_out, N);
    // decode (R8-exact)
    gemm_k<64, 128, 8, true, false, false><<<gb, TPB, 0, stream>>>(z_out, Wd, bd, x_recon, N);
}